// Round 2
// baseline (1457.780 us; speedup 1.0000x reference)
//
#include <hip/hip_runtime.h>

#define NN 100000
#define FIN 512
#define H1D 64
#define H2D 128
#define CD 40
#define BNEPS 1e-5f

// ---------------- graph preprocessing ----------------

__global__ void hist_k(const int* __restrict__ dst, int E, int* __restrict__ deg) {
    int i = blockIdx.x * blockDim.x + threadIdx.x;
    int stride = gridDim.x * blockDim.x;
    for (; i < E; i += stride) atomicAdd(&deg[dst[i]], 1);
}

// single-block exclusive scan over deg[NN] -> rowstart, cursor; dinv = rsqrt(deg+1)
__global__ __launch_bounds__(1024) void scan_k(const int* __restrict__ deg,
                                               int* __restrict__ rowstart,
                                               int* __restrict__ cursor,
                                               float* __restrict__ dinv, int E) {
    __shared__ int sh[1024];
    int tid = threadIdx.x;
    const int chunk = (NN + 1023) / 1024;  // 98
    int start = tid * chunk;
    int end = start + chunk; if (end > NN) end = NN;
    int s = 0;
    for (int i = start; i < end; ++i) s += deg[i];
    sh[tid] = s;
    __syncthreads();
    for (int off = 1; off < 1024; off <<= 1) {
        int v = (tid >= off) ? sh[tid - off] : 0;
        __syncthreads();
        sh[tid] += v;
        __syncthreads();
    }
    int base = (tid == 0) ? 0 : sh[tid - 1];
    for (int i = start; i < end; ++i) {
        rowstart[i] = base;
        cursor[i] = base;
        int d = deg[i];
        base += d;
        dinv[i] = rsqrtf((float)(d + 1));
    }
    if (tid == 0) rowstart[NN] = E;
}

__global__ void fill_k(const int* __restrict__ src, const int* __restrict__ dst, int E,
                       int* __restrict__ cursor, int* __restrict__ csr) {
    int i = blockIdx.x * blockDim.x + threadIdx.x;
    int stride = gridDim.x * blockDim.x;
    for (; i < E; i += stride) {
        int d = dst[i];
        int pos = atomicAdd(&cursor[d], 1);
        csr[pos] = src[i];
    }
}

// ---------------- GEMM1: t1 = (x @ W1) * dinv ----------------
// f32 VALU GEMM. Block: 64 rows x 64 cols, 256 threads, each 4x4 outputs, K chunks of 32.
__global__ __launch_bounds__(256) void gemm1_k(const float* __restrict__ x,
                                               const float* __restrict__ W1,
                                               const float* __restrict__ dinv,
                                               float* __restrict__ t1) {
    __shared__ float sx[32 * 68];  // [k][row], pad 68 keeps 16B alignment + spreads banks
    __shared__ float sw[32 * 68];  // [k][col]
    int tid = threadIdx.x;
    int r0 = blockIdx.x * 64;
    int rg = tid >> 4;    // 0..15 row group
    int cg = tid & 15;    // 0..15 col group
    float acc[4][4];
#pragma unroll
    for (int i = 0; i < 4; ++i)
#pragma unroll
        for (int j = 0; j < 4; ++j) acc[i][j] = 0.f;

    for (int kb = 0; kb < FIN; kb += 32) {
        __syncthreads();
#pragma unroll
        for (int i = 0; i < 2; ++i) {
            int q = tid + i * 256;
            // x tile: 64 rows x 32 k, transposed into sx[k][row]
            int row = q >> 3, k4 = q & 7;
            int grow = r0 + row;
            int gr = grow < NN ? grow : NN - 1;
            float4 v = *(const float4*)(x + (size_t)gr * FIN + kb + k4 * 4);
            sx[(k4 * 4 + 0) * 68 + row] = v.x;
            sx[(k4 * 4 + 1) * 68 + row] = v.y;
            sx[(k4 * 4 + 2) * 68 + row] = v.z;
            sx[(k4 * 4 + 3) * 68 + row] = v.w;
            // W tile: 32 k x 64 cols, straight copy
            int kk = q >> 4, c4 = (q & 15) * 4;
            *(float4*)&sw[kk * 68 + c4] = *(const float4*)(W1 + (size_t)(kb + kk) * H1D + c4);
        }
        __syncthreads();
#pragma unroll
        for (int k = 0; k < 32; ++k) {
            float4 a = *(const float4*)&sx[k * 68 + rg * 4];
            float4 b = *(const float4*)&sw[k * 68 + cg * 4];
            acc[0][0] += a.x * b.x; acc[0][1] += a.x * b.y; acc[0][2] += a.x * b.z; acc[0][3] += a.x * b.w;
            acc[1][0] += a.y * b.x; acc[1][1] += a.y * b.y; acc[1][2] += a.y * b.z; acc[1][3] += a.y * b.w;
            acc[2][0] += a.z * b.x; acc[2][1] += a.z * b.y; acc[2][2] += a.z * b.z; acc[2][3] += a.z * b.w;
            acc[3][0] += a.w * b.x; acc[3][1] += a.w * b.y; acc[3][2] += a.w * b.z; acc[3][3] += a.w * b.w;
        }
    }
#pragma unroll
    for (int i = 0; i < 4; ++i) {
        int r = r0 + rg * 4 + i;
        if (r < NN) {
            float dv = dinv[r];
            float4 o = { acc[i][0] * dv, acc[i][1] * dv, acc[i][2] * dv, acc[i][3] * dv };
            *(float4*)&t1[(size_t)r * H1D + cg * 4] = o;
        }
    }
}

// ---------------- aggregation over 64-dim rows, one wave per node ----------------
// MODE 1: out = relu( (dinv*sum)*sc + sv ) * dinv   (layer1 BN/bias/relu, pre-scaled for next agg)
// MODE 2: out = dinv*sum                            (u2 = M h1)
template <int MODE>
__global__ __launch_bounds__(256) void agg64_k(const float* __restrict__ tin,
                                               float* __restrict__ tout,
                                               const int* __restrict__ rowstart,
                                               const int* __restrict__ csr,
                                               const float* __restrict__ dinv,
                                               const float* __restrict__ g,
                                               const float* __restrict__ bt,
                                               const float* __restrict__ rm,
                                               const float* __restrict__ rv,
                                               const float* __restrict__ b) {
    int wid = (blockIdx.x * blockDim.x + threadIdx.x) >> 6;
    int lane = threadIdx.x & 63;
    if (wid >= NN) return;
    int rs = rowstart[wid], re = rowstart[wid + 1];
    float acc = tin[(size_t)wid * H1D + lane];  // self loop
    int i = rs;
    int n4 = rs + ((re - rs) & ~3);
    for (; i < n4; i += 4) {
        int s0 = csr[i], s1 = csr[i + 1], s2 = csr[i + 2], s3 = csr[i + 3];
        float a0 = tin[(size_t)s0 * H1D + lane];
        float a1 = tin[(size_t)s1 * H1D + lane];
        float a2 = tin[(size_t)s2 * H1D + lane];
        float a3 = tin[(size_t)s3 * H1D + lane];
        acc += (a0 + a1) + (a2 + a3);
    }
    for (; i < re; ++i) acc += tin[(size_t)csr[i] * H1D + lane];
    float dv = dinv[wid];
    float z = acc * dv;
    if (MODE == 1) {
        float sc = g[lane] * rsqrtf(rv[lane] + BNEPS);
        float sv = (b[lane] - rm[lane]) * sc + bt[lane];
        z = fmaxf(z * sc + sv, 0.f) * dv;
    }
    tout[(size_t)wid * H1D + lane] = z;
}

// ---------------- fused GEMM2 + BN2 + ReLU + GEMM3 ----------------
// g3 = relu(BN(u2@W2 + b2)) @ W3 * dinv   (one thread per node)
__global__ __launch_bounds__(256) void p2p3_k(const float* __restrict__ u2,
                                              const float* __restrict__ W2,
                                              const float* __restrict__ b2,
                                              const float* __restrict__ W3,
                                              const float* __restrict__ g2,
                                              const float* __restrict__ bt2,
                                              const float* __restrict__ rm2,
                                              const float* __restrict__ rv2,
                                              const float* __restrict__ dinv,
                                              float* __restrict__ g3) {
    __shared__ float sW2[H1D * H2D];   // 32 KB, [l][f]
    __shared__ float sW3[H2D * CD];    // 20 KB, [f][c]
    __shared__ float sc2[H2D], sh2[H2D];
    int tid = threadIdx.x;
    for (int i = tid; i < H1D * H2D; i += 256) sW2[i] = W2[i];
    for (int i = tid; i < H2D * CD; i += 256) sW3[i] = W3[i];
    if (tid < H2D) {
        float s = g2[tid] * rsqrtf(rv2[tid] + BNEPS);
        sc2[tid] = s;
        sh2[tid] = (b2[tid] - rm2[tid]) * s + bt2[tid];
    }
    __syncthreads();
    int node = blockIdx.x * 256 + tid;
    if (node >= NN) return;
    float u[H1D];
    const float4* up = (const float4*)(u2 + (size_t)node * H1D);
#pragma unroll
    for (int i = 0; i < 16; ++i) {
        float4 v = up[i];
        u[4 * i] = v.x; u[4 * i + 1] = v.y; u[4 * i + 2] = v.z; u[4 * i + 3] = v.w;
    }
    float gacc[CD];
#pragma unroll
    for (int c = 0; c < CD; ++c) gacc[c] = 0.f;
    // f in chunks of 32 to bound register pressure
    for (int fc = 0; fc < H2D; fc += 32) {
        float a[32];
#pragma unroll
        for (int j = 0; j < 32; ++j) a[j] = 0.f;
        for (int l = 0; l < H1D; ++l) {
            float ul = u[l];
            const float4* wr = (const float4*)&sW2[l * H2D + fc];
#pragma unroll
            for (int j = 0; j < 8; ++j) {
                float4 w = wr[j];   // broadcast read (uniform address)
                a[4 * j]     += ul * w.x;
                a[4 * j + 1] += ul * w.y;
                a[4 * j + 2] += ul * w.z;
                a[4 * j + 3] += ul * w.w;
            }
        }
#pragma unroll
        for (int j = 0; j < 32; ++j) {
            int f = fc + j;
            float h = fmaxf(a[j] * sc2[f] + sh2[f], 0.f);
            const float4* w3r = (const float4*)&sW3[f * CD];  // 160B rows -> 16B aligned
#pragma unroll
            for (int c = 0; c < 10; ++c) {
                float4 w = w3r[c];
                gacc[4 * c]     += h * w.x;
                gacc[4 * c + 1] += h * w.y;
                gacc[4 * c + 2] += h * w.z;
                gacc[4 * c + 3] += h * w.w;
            }
        }
    }
    float dv = dinv[node];
    float* op = g3 + (size_t)node * CD;
#pragma unroll
    for (int c = 0; c < 10; ++c) {
        float4 o = { gacc[4 * c] * dv, gacc[4 * c + 1] * dv, gacc[4 * c + 2] * dv, gacc[4 * c + 3] * dv };
        *(float4*)&op[4 * c] = o;
    }
}

// ---------------- aggregation over 40-dim + bias + log_softmax ----------------
__global__ __launch_bounds__(256) void agg40_k(const float* __restrict__ g3,
                                               const float* __restrict__ b3,
                                               const int* __restrict__ rowstart,
                                               const int* __restrict__ csr,
                                               const float* __restrict__ dinv,
                                               float* __restrict__ out) {
    int wid = (blockIdx.x * blockDim.x + threadIdx.x) >> 6;
    int lane = threadIdx.x & 63;
    if (wid >= NN) return;
    int col = lane < CD ? lane : 0;
    int rs = rowstart[wid], re = rowstart[wid + 1];
    float acc = g3[(size_t)wid * CD + col];  // self loop
    int i = rs;
    int n4 = rs + ((re - rs) & ~3);
    for (; i < n4; i += 4) {
        int s0 = csr[i], s1 = csr[i + 1], s2 = csr[i + 2], s3 = csr[i + 3];
        float a0 = g3[(size_t)s0 * CD + col];
        float a1 = g3[(size_t)s1 * CD + col];
        float a2 = g3[(size_t)s2 * CD + col];
        float a3 = g3[(size_t)s3 * CD + col];
        acc += (a0 + a1) + (a2 + a3);
    }
    for (; i < re; ++i) acc += g3[(size_t)csr[i] * CD + col];
    float dv = dinv[wid];
    float z = (lane < CD) ? (acc * dv + b3[col]) : -1e30f;
    float m = z;
#pragma unroll
    for (int off = 32; off > 0; off >>= 1) m = fmaxf(m, __shfl_xor(m, off));
    float e = (lane < CD) ? __expf(z - m) : 0.f;
    float s = e;
#pragma unroll
    for (int off = 32; off > 0; off >>= 1) s += __shfl_xor(s, off);
    if (lane < CD) out[(size_t)wid * CD + lane] = z - m - __logf(s);
}

// ---------------- launcher ----------------

extern "C" void kernel_launch(void* const* d_in, const int* in_sizes, int n_in,
                              void* d_out, int out_size, void* d_ws, size_t ws_size,
                              hipStream_t stream) {
    (void)n_in; (void)out_size; (void)ws_size;
    const float* x   = (const float*)d_in[0];
    const int*   ei  = (const int*)d_in[1];
    const float* W1  = (const float*)d_in[2];
    const float* b1  = (const float*)d_in[3];
    const float* W2  = (const float*)d_in[4];
    const float* b2  = (const float*)d_in[5];
    const float* W3  = (const float*)d_in[6];
    const float* b3  = (const float*)d_in[7];
    const float* g1  = (const float*)d_in[8];
    const float* bt1 = (const float*)d_in[9];
    const float* rm1 = (const float*)d_in[10];
    const float* rv1 = (const float*)d_in[11];
    const float* g2  = (const float*)d_in[12];
    const float* bt2 = (const float*)d_in[13];
    const float* rm2 = (const float*)d_in[14];
    const float* rv2 = (const float*)d_in[15];
    float* out = (float*)d_out;
    const int E = in_sizes[1] / 2;

    char* w = (char*)d_ws;
    auto alloc = [&](size_t bytes) { char* p = w; w += (bytes + 511) & ~(size_t)511; return p; };
    int*   deg      = (int*)alloc((size_t)NN * 4);
    int*   rowstart = (int*)alloc((size_t)(NN + 1) * 4);
    int*   cursor   = (int*)alloc((size_t)NN * 4);
    float* dinv     = (float*)alloc((size_t)NN * 4);
    int*   csr      = (int*)alloc((size_t)E * 4);
    float* t1       = (float*)alloc((size_t)NN * H1D * 4);   // also reused as u2
    float* t2       = (float*)alloc((size_t)NN * H1D * 4);
    float* g3       = (float*)alloc((size_t)NN * CD * 4);

    hipMemsetAsync(deg, 0, (size_t)NN * 4, stream);
    hist_k<<<1024, 256, 0, stream>>>(ei + E, E, deg);
    scan_k<<<1, 1024, 0, stream>>>(deg, rowstart, cursor, dinv, E);
    fill_k<<<1024, 256, 0, stream>>>(ei, ei + E, E, cursor, csr);
    gemm1_k<<<(NN + 63) / 64, 256, 0, stream>>>(x, W1, dinv, t1);
    agg64_k<1><<<(NN + 3) / 4, 256, 0, stream>>>(t1, t2, rowstart, csr, dinv, g1, bt1, rm1, rv1, b1);
    agg64_k<2><<<(NN + 3) / 4, 256, 0, stream>>>(t2, t1, rowstart, csr, dinv, nullptr, nullptr, nullptr, nullptr, nullptr);
    p2p3_k<<<(NN + 255) / 256, 256, 0, stream>>>(t1, W2, b2, W3, g2, bt2, rm2, rv2, dinv, g3);
    agg40_k<<<(NN + 3) / 4, 256, 0, stream>>>(g3, b3, rowstart, csr, dinv, out);
}